// Round 1
// baseline (171.777 us; speedup 1.0000x reference)
//
#include <hip/hip_runtime.h>
#include <hip/hip_bf16.h>
#include <cstdint>

#define BB 32
#define LD 2048
#define LQ 512
#define DD 256
#define BM 128
#define BN 128
#define BK 32

typedef _Float16 half8 __attribute__((ext_vector_type(8)));
typedef _Float16 half4 __attribute__((ext_vector_type(4)));
typedef float float4v __attribute__((ext_vector_type(4)));

// tanh(x) = (e^{2x}-1)/(e^{2x}+1) = 1 - 2/(e^{2x}+1); inf/0 saturate correctly.
__device__ __forceinline__ float tanh_fast(float x) {
    float e = __expf(2.0f * x);
    return 1.0f - 2.0f / (e + 1.0f);
}

// async 16B global->LDS; LDS dest is wave-uniform base + lane*16 (HW adds lane offset)
__device__ __forceinline__ void load_lds16(const void* g, void* s) {
    __builtin_amdgcn_global_load_lds((const __attribute__((address_space(1))) void*)g,
                                     (__attribute__((address_space(3))) void*)s, 16, 0, 0);
}

// fp32 -> f16 convert, 8 elems/thread
__global__ __launch_bounds__(256) void kconv(const float* __restrict__ src,
                                             _Float16* __restrict__ dst, int n8) {
    int i = blockIdx.x * 256 + threadIdx.x;
    if (i >= n8) return;
    const float4v* s = (const float4v*)src + (size_t)i * 2;
    float4v a = s[0], c = s[1];
    half8 h = {(_Float16)a[0], (_Float16)a[1], (_Float16)a[2], (_Float16)a[3],
               (_Float16)c[0], (_Float16)c[1], (_Float16)c[2], (_Float16)c[3]};
    *((half8*)dst + i) = h;
}

// K1: per-batch tanh(Q Doc^T) with fused row/col sums into logits (never materializes S).
// 128x128 tile, BK=32, 4 waves each computing a 64x64 quadrant (4x4 MFMA 16x16x32 tiles).
template <bool F16SRC>
__global__ __launch_bounds__(256, 2) void k1(const void* __restrict__ qsrc,
                                             const void* __restrict__ dsrc,
                                             float* __restrict__ alog,   // [B][LD]
                                             float* __restrict__ blog) { // [B][LQ]
    __shared__ _Float16 sQ[BM * BK];
    __shared__ _Float16 sD[BN * BK];
    const int bq = blockIdx.x, bt = blockIdx.y, b = blockIdx.z;
    const int tid = threadIdx.x;
    const int lane = tid & 63;
    const int wave = tid >> 6;
    const int r16 = lane & 15;
    const int q4 = lane >> 4;
    const int mb = (wave >> 1) * 64, nb = (wave & 1) * 64;

    float4v acc[4][4];
    float4v zero = {0.f, 0.f, 0.f, 0.f};
#pragma unroll
    for (int m = 0; m < 4; m++)
#pragma unroll
        for (int n = 0; n < 4; n++) acc[m][n] = zero;

    for (int kk = 0; kk < DD; kk += BK) {
        __syncthreads(); // previous iteration's LDS reads done
        if constexpr (F16SRC) {
            const _Float16* Qh = (const _Float16*)qsrc + ((size_t)b * LQ + bq * BM) * DD;
            const _Float16* Dh = (const _Float16*)dsrc + ((size_t)b * LD + bt * BN) * DD;
#pragma unroll
            for (int j = 0; j < 2; j++) {
                int c = 2 * wave + j;                // 1KB LDS chunk = 16 rows of 64B
                int row = 16 * c + (lane >> 2);
                int col = (lane & 3) * 8;            // f16 elems
                load_lds16(Qh + (size_t)row * DD + kk + col, &sQ[c * 512]);
                load_lds16(Dh + (size_t)row * DD + kk + col, &sD[c * 512]);
            }
        } else {
            const float* Qf = (const float*)qsrc + ((size_t)b * LQ + bq * BM) * DD;
            const float* Df = (const float*)dsrc + ((size_t)b * LD + bt * BN) * DD;
#pragma unroll
            for (int i = 0; i < 4; i++) {
                int f = tid + 256 * i;               // float4 id within 128x32 tile
                int row = f >> 3, c = f & 7;
                float4v v = *(const float4v*)(Qf + (size_t)row * DD + kk + 4 * c);
                half4 h = {(_Float16)v[0], (_Float16)v[1], (_Float16)v[2], (_Float16)v[3]};
                *(half4*)(&sQ[row * BK + 4 * c]) = h;
                float4v w = *(const float4v*)(Df + (size_t)row * DD + kk + 4 * c);
                half4 h2 = {(_Float16)w[0], (_Float16)w[1], (_Float16)w[2], (_Float16)w[3]};
                *(half4*)(&sD[row * BK + 4 * c]) = h2;
            }
        }
        __syncthreads(); // staging complete (compiler drains vmcnt before s_barrier)

        half8 af[4], bf[4];
#pragma unroll
        for (int m = 0; m < 4; m++) af[m] = *(const half8*)(&sQ[(mb + 16 * m + r16) * BK + 8 * q4]);
#pragma unroll
        for (int n = 0; n < 4; n++) bf[n] = *(const half8*)(&sD[(nb + 16 * n + r16) * BK + 8 * q4]);
#pragma unroll
        for (int m = 0; m < 4; m++)
#pragma unroll
            for (int n = 0; n < 4; n++)
                acc[m][n] = __builtin_amdgcn_mfma_f32_16x16x32_f16(af[m], bf[n], acc[m][n], 0, 0, 0);
    }

    // Epilogue: tanh, then row sums (-> beta logits over q) and col sums (-> alpha logits over t).
    // C/D layout: row = 4*q4 + r, col = lane&15 (verified m89/m91, dtype-independent).
    float rsum[4][4];
    float csum[4];
#pragma unroll
    for (int m = 0; m < 4; m++)
#pragma unroll
        for (int r = 0; r < 4; r++) rsum[m][r] = 0.f;
#pragma unroll
    for (int n = 0; n < 4; n++) csum[n] = 0.f;

#pragma unroll
    for (int m = 0; m < 4; m++)
#pragma unroll
        for (int n = 0; n < 4; n++) {
            float t0 = tanh_fast(acc[m][n][0]);
            float t1 = tanh_fast(acc[m][n][1]);
            float t2 = tanh_fast(acc[m][n][2]);
            float t3 = tanh_fast(acc[m][n][3]);
            csum[n] += t0 + t1 + t2 + t3;
            rsum[m][0] += t0;
            rsum[m][1] += t1;
            rsum[m][2] += t2;
            rsum[m][3] += t3;
        }

    // row sums: butterfly over the 16 cols (lanes sharing q4), then 4 lanes commit 4 rows
#pragma unroll
    for (int m = 0; m < 4; m++) {
#pragma unroll
        for (int r = 0; r < 4; r++) {
            float v = rsum[m][r];
            v += __shfl_xor(v, 1);
            v += __shfl_xor(v, 2);
            v += __shfl_xor(v, 4);
            v += __shfl_xor(v, 8);
            rsum[m][r] = v;
        }
        if (r16 < 4) {
            float v = (r16 == 0) ? rsum[m][0] : (r16 == 1) ? rsum[m][1] : (r16 == 2) ? rsum[m][2] : rsum[m][3];
            atomicAdd(blog + b * LQ + bq * BM + mb + 16 * m + 4 * q4 + r16, v);
        }
    }
    // col sums: butterfly across the 4 quads, lanes 0..15 commit 16 cols
#pragma unroll
    for (int n = 0; n < 4; n++) {
        float v = csum[n];
        v += __shfl_xor(v, 16);
        v += __shfl_xor(v, 32);
        if (lane < 16) atomicAdd(alog + b * LD + bt * BN + nb + 16 * n + lane, v);
    }
}

// K2: alpha = softmax(alog)*dmask renormalized; beta likewise. One block per softmax row.
__global__ __launch_bounds__(256) void k2(const float* __restrict__ alog, const float* __restrict__ blog,
                                          const float* __restrict__ dmask, const float* __restrict__ qmask,
                                          float* __restrict__ alpha, float* __restrict__ beta) {
    int blk = blockIdx.x;
    const float *lg, *mk;
    float* out;
    int n;
    if (blk < BB) {
        lg = alog + blk * LD; mk = dmask + blk * LD; out = alpha + blk * LD; n = LD;
    } else {
        int b = blk - BB;
        lg = blog + b * LQ; mk = qmask + b * LQ; out = beta + b * LQ; n = LQ;
    }
    int tid = threadIdx.x, lane = tid & 63, wave = tid >> 6;
    __shared__ float sm[4], ss[4];
    float mx = -3.0e38f;
    for (int i = tid; i < n; i += 256) mx = fmaxf(mx, lg[i]);
#pragma unroll
    for (int s = 1; s < 64; s <<= 1) mx = fmaxf(mx, __shfl_xor(mx, s));
    if (lane == 0) sm[wave] = mx;
    __syncthreads();
    mx = fmaxf(fmaxf(sm[0], sm[1]), fmaxf(sm[2], sm[3]));
    float sum = 0.f;
    for (int i = tid; i < n; i += 256) sum += __expf(lg[i] - mx) * mk[i];
#pragma unroll
    for (int s = 1; s < 64; s <<= 1) sum += __shfl_xor(sum, s);
    if (lane == 0) ss[wave] = sum;
    __syncthreads();
    sum = ss[0] + ss[1] + ss[2] + ss[3];
    float inv = 1.0f / sum;
    for (int i = tid; i < n; i += 256) out[i] = __expf(lg[i] - mx) * mk[i] * inv;
}

// K3: doc_vec[b,d] = sum_t alpha[b,t] doc[b,t,d]; que_vec[b,d] = sum_q beta[b,q] query[b,q,d].
// Chunked over positions, fp32 atomics into zero-initialized d_out.
template <bool F16SRC>
__global__ __launch_bounds__(256) void k3(const float* __restrict__ docf, const float* __restrict__ qryf,
                                          const _Float16* __restrict__ dh, const _Float16* __restrict__ qh,
                                          const float* __restrict__ alpha, const float* __restrict__ beta,
                                          float* __restrict__ out) {
    int blk = blockIdx.x, d = threadIdx.x;
    if (blk < BB * 16) {
        int b = blk >> 4, ch = blk & 15;
        const float* w = alpha + b * LD + ch * 128;
        size_t base = ((size_t)b * LD + ch * 128) * DD + d;
        float acc = 0.f;
        for (int t = 0; t < 128; t++) {
            float x = F16SRC ? (float)dh[base + (size_t)t * DD] : docf[base + (size_t)t * DD];
            acc += w[t] * x;
        }
        atomicAdd(out + b * 2 * DD + d, acc);
    } else {
        int bk2 = blk - BB * 16;
        int b = bk2 >> 2, ch = bk2 & 3;
        const float* w = beta + b * LQ + ch * 128;
        size_t base = ((size_t)b * LQ + ch * 128) * DD + d;
        float acc = 0.f;
        for (int t = 0; t < 128; t++) {
            float x = F16SRC ? (float)qh[base + (size_t)t * DD] : qryf[base + (size_t)t * DD];
            acc += w[t] * x;
        }
        atomicAdd(out + b * 2 * DD + DD + d, acc);
    }
}

extern "C" void kernel_launch(void* const* d_in, const int* in_sizes, int n_in,
                              void* d_out, int out_size, void* d_ws, size_t ws_size,
                              hipStream_t stream) {
    (void)in_sizes; (void)n_in; (void)out_size;
    const float* doc = (const float*)d_in[0];
    const float* qry = (const float*)d_in[1];
    const float* dmask = (const float*)d_in[2];
    const float* qmask = (const float*)d_in[3];
    float* out = (float*)d_out;

    float* alog = (float*)d_ws;                 // [B][LD]
    float* blog = alog + BB * LD;               // [B][LQ]
    float* alpha = blog + BB * LQ;              // [B][LD]
    float* beta = alpha + BB * LD;              // [B][LQ]
    _Float16* dh = (_Float16*)(beta + BB * LQ); // [B][LD][D] f16
    _Float16* qh = dh + (size_t)BB * LD * DD;   // [B][LQ][D] f16
    size_t needed = (size_t)(2 * BB * LD + 2 * BB * LQ) * 4 +
                    ((size_t)BB * LD * DD + (size_t)BB * LQ * DD) * 2;
    bool useF16 = ws_size >= needed;

    hipMemsetAsync(alog, 0, (size_t)(BB * LD + BB * LQ) * 4, stream);
    hipMemsetAsync(d_out, 0, (size_t)BB * 2 * DD * 4, stream);

    if (useF16) {
        kconv<<<(BB * LD * DD / 8 + 255) / 256, 256, 0, stream>>>(doc, dh, BB * LD * DD / 8);
        kconv<<<(BB * LQ * DD / 8 + 255) / 256, 256, 0, stream>>>(qry, qh, BB * LQ * DD / 8);
        k1<true><<<dim3(LQ / BM, LD / BN, BB), 256, 0, stream>>>(qh, dh, alog, blog);
    } else {
        k1<false><<<dim3(LQ / BM, LD / BN, BB), 256, 0, stream>>>(qry, doc, alog, blog);
    }
    k2<<<2 * BB, 256, 0, stream>>>(alog, blog, dmask, qmask, alpha, beta);
    if (useF16) {
        k3<true><<<BB * 16 + BB * 4, 256, 0, stream>>>(doc, qry, dh, qh, alpha, beta, out);
    } else {
        k3<false><<<BB * 16 + BB * 4, 256, 0, stream>>>(doc, qry, dh, qh, alpha, beta, out);
    }
}

// Round 2
// 169.062 us; speedup vs baseline: 1.0161x; 1.0161x over previous
//
#include <hip/hip_runtime.h>
#include <hip/hip_bf16.h>
#include <cstdint>

#define BB 32
#define LD 2048
#define LQ 512
#define DD 256
#define BM 128
#define BN 128
#define BK 64

typedef _Float16 half8 __attribute__((ext_vector_type(8)));
typedef _Float16 half4 __attribute__((ext_vector_type(4)));
typedef float float4v __attribute__((ext_vector_type(4)));

__device__ __forceinline__ float tanh_fast(float x) {
    float e = __expf(2.0f * x);
    return 1.0f - 2.0f / (e + 1.0f);
}

// async 16B global->LDS; LDS dest = wave-uniform base + lane*16 (HW adds lane offset)
__device__ __forceinline__ void load_lds16(const void* g, void* s) {
    __builtin_amdgcn_global_load_lds((const __attribute__((address_space(1))) void*)g,
                                     (__attribute__((address_space(3))) void*)s, 16, 0, 0);
}

#define DOCN8 (BB * LD * DD / 8)
#define QRYN8 (BB * LQ * DD / 8)

// fp32 -> f16 convert of doc then query, one dispatch, 8 elems/thread
__global__ __launch_bounds__(256) void kconv(const float* __restrict__ doc,
                                             const float* __restrict__ qry,
                                             _Float16* __restrict__ dh,
                                             _Float16* __restrict__ qh) {
    int i = blockIdx.x * 256 + threadIdx.x;
    const float* src;
    _Float16* dst;
    int idx;
    if (i < DOCN8) { src = doc; dst = dh; idx = i; }
    else           { src = qry; dst = qh; idx = i - DOCN8; }
    const float4v* s = (const float4v*)src + (size_t)idx * 2;
    float4v a = s[0], c = s[1];
    half8 h = {(_Float16)a[0], (_Float16)a[1], (_Float16)a[2], (_Float16)a[3],
               (_Float16)c[0], (_Float16)c[1], (_Float16)c[2], (_Float16)c[3]};
    *((half8*)dst + idx) = h;
}

// K1: per-batch tanh(Q Doc^T) with fused row/col sums into logits (never materializes S).
// 128x128 tile, BK=64, 4 waves each computing a 64x64 quadrant (4x4 MFMA 16x16x32, 2 k-steps).
// LDS layout XOR-swizzled: physical 16B chunk p of row r holds logical k-chunk p ^ (r&7),
// arranged at staging time via the lane->global-address map (LDS side of global_load_lds is
// fixed to base+16*lane). Fragment reads then hit all 8 bank groups 2-way (free).
template <bool F16SRC>
__global__ __launch_bounds__(256) void k1(const void* __restrict__ qsrc,
                                          const void* __restrict__ dsrc,
                                          float* __restrict__ alog,   // [B][LD]
                                          float* __restrict__ blog) { // [B][LQ]
    __shared__ _Float16 sQ[BM * BK]; // 16KB
    __shared__ _Float16 sD[BN * BK]; // 16KB
    const int bq = blockIdx.x, bt = blockIdx.y, b = blockIdx.z;
    const int tid = threadIdx.x;
    const int lane = tid & 63;
    const int wave = tid >> 6;
    const int r16 = lane & 15;
    const int q4 = lane >> 4;
    const int mb = (wave >> 1) * 64, nb = (wave & 1) * 64;

    float4v acc[4][4];
    float4v zero = {0.f, 0.f, 0.f, 0.f};
#pragma unroll
    for (int m = 0; m < 4; m++)
#pragma unroll
        for (int n = 0; n < 4; n++) acc[m][n] = zero;

    // staging lane map: 1KB chunk = 8 rows x 128B; lane -> (row-in-chunk, phys 16B pos)
    const int lrow = lane >> 3;                 // 0..7
    const int lcol = ((lane & 7) ^ lrow) * 8;   // logical k offset (f16) for this phys pos

    for (int kk = 0; kk < DD; kk += BK) {
        __syncthreads(); // previous iteration's LDS reads done
        if constexpr (F16SRC) {
            const _Float16* Qh = (const _Float16*)qsrc + ((size_t)b * LQ + bq * BM) * DD;
            const _Float16* Dh = (const _Float16*)dsrc + ((size_t)b * LD + bt * BN) * DD;
#pragma unroll
            for (int j = 0; j < 4; j++) {
                int c = wave * 4 + j;           // chunk 0..15 (rows 8c..8c+7)
                int row = 8 * c + lrow;
                load_lds16(Qh + (size_t)row * DD + kk + lcol, &sQ[c * 512]);
                load_lds16(Dh + (size_t)row * DD + kk + lcol, &sD[c * 512]);
            }
        } else {
            const float* Qf = (const float*)qsrc + ((size_t)b * LQ + bq * BM) * DD;
            const float* Df = (const float*)dsrc + ((size_t)b * LD + bt * BN) * DD;
#pragma unroll
            for (int i = 0; i < 8; i++) {
                int f = tid + 256 * i;          // float4 id within 128x64 tile
                int row = f >> 4, c = f & 15;   // c: 16 float4 per row
                int c2 = c >> 1, hlf = c & 1;   // 16B LDS chunk + half
                int p = c2 ^ (row & 7);
                float4v v = *(const float4v*)(Qf + (size_t)row * DD + kk + 4 * c);
                half4 h = {(_Float16)v[0], (_Float16)v[1], (_Float16)v[2], (_Float16)v[3]};
                *(half4*)(&sQ[row * BK + p * 8 + hlf * 4]) = h;
                float4v w = *(const float4v*)(Df + (size_t)row * DD + kk + 4 * c);
                half4 h2 = {(_Float16)w[0], (_Float16)w[1], (_Float16)w[2], (_Float16)w[3]};
                *(half4*)(&sD[row * BK + p * 8 + hlf * 4]) = h2;
            }
        }
        __syncthreads(); // staging complete

#pragma unroll
        for (int kk2 = 0; kk2 < 2; kk2++) {
            const int sw = ((4 * kk2 + q4) ^ (r16 & 7)) * 8;
            half8 af[4], bf[4];
#pragma unroll
            for (int m = 0; m < 4; m++) af[m] = *(const half8*)(&sQ[(mb + 16 * m + r16) * BK + sw]);
#pragma unroll
            for (int n = 0; n < 4; n++) bf[n] = *(const half8*)(&sD[(nb + 16 * n + r16) * BK + sw]);
#pragma unroll
            for (int m = 0; m < 4; m++)
#pragma unroll
                for (int n = 0; n < 4; n++)
                    acc[m][n] = __builtin_amdgcn_mfma_f32_16x16x32_f16(af[m], bf[n], acc[m][n], 0, 0, 0);
        }
    }

    // Epilogue: tanh, then row sums (-> beta logits over q) and col sums (-> alpha logits over t).
    // C/D layout: row = 4*q4 + r, col = lane&15.
    float rsum[4][4];
    float csum[4];
#pragma unroll
    for (int m = 0; m < 4; m++)
#pragma unroll
        for (int r = 0; r < 4; r++) rsum[m][r] = 0.f;
#pragma unroll
    for (int n = 0; n < 4; n++) csum[n] = 0.f;

#pragma unroll
    for (int m = 0; m < 4; m++)
#pragma unroll
        for (int n = 0; n < 4; n++) {
            float t0 = tanh_fast(acc[m][n][0]);
            float t1 = tanh_fast(acc[m][n][1]);
            float t2 = tanh_fast(acc[m][n][2]);
            float t3 = tanh_fast(acc[m][n][3]);
            csum[n] += t0 + t1 + t2 + t3;
            rsum[m][0] += t0;
            rsum[m][1] += t1;
            rsum[m][2] += t2;
            rsum[m][3] += t3;
        }

#pragma unroll
    for (int m = 0; m < 4; m++) {
#pragma unroll
        for (int r = 0; r < 4; r++) {
            float v = rsum[m][r];
            v += __shfl_xor(v, 1);
            v += __shfl_xor(v, 2);
            v += __shfl_xor(v, 4);
            v += __shfl_xor(v, 8);
            rsum[m][r] = v;
        }
        if (r16 < 4) {
            float v = (r16 == 0) ? rsum[m][0] : (r16 == 1) ? rsum[m][1] : (r16 == 2) ? rsum[m][2] : rsum[m][3];
            atomicAdd(blog + b * LQ + bq * BM + mb + 16 * m + 4 * q4 + r16, v);
        }
    }
#pragma unroll
    for (int n = 0; n < 4; n++) {
        float v = csum[n];
        v += __shfl_xor(v, 16);
        v += __shfl_xor(v, 32);
        if (lane < 16) atomicAdd(alog + b * LD + bt * BN + nb + 16 * n + lane, v);
    }
}

// K2: alpha = softmax(alog)*dmask renormalized; beta likewise. One block per softmax row.
__global__ __launch_bounds__(256) void k2(const float* __restrict__ alog, const float* __restrict__ blog,
                                          const float* __restrict__ dmask, const float* __restrict__ qmask,
                                          float* __restrict__ alpha, float* __restrict__ beta) {
    int blk = blockIdx.x;
    const float *lg, *mk;
    float* out;
    int n;
    if (blk < BB) {
        lg = alog + blk * LD; mk = dmask + blk * LD; out = alpha + blk * LD; n = LD;
    } else {
        int b = blk - BB;
        lg = blog + b * LQ; mk = qmask + b * LQ; out = beta + b * LQ; n = LQ;
    }
    int tid = threadIdx.x, lane = tid & 63, wave = tid >> 6;
    __shared__ float sm[4], ss[4];
    float mx = -3.0e38f;
    for (int i = tid; i < n; i += 256) mx = fmaxf(mx, lg[i]);
#pragma unroll
    for (int s = 1; s < 64; s <<= 1) mx = fmaxf(mx, __shfl_xor(mx, s));
    if (lane == 0) sm[wave] = mx;
    __syncthreads();
    mx = fmaxf(fmaxf(sm[0], sm[1]), fmaxf(sm[2], sm[3]));
    float sum = 0.f;
    for (int i = tid; i < n; i += 256) sum += __expf(lg[i] - mx) * mk[i];
#pragma unroll
    for (int s = 1; s < 64; s <<= 1) sum += __shfl_xor(sum, s);
    if (lane == 0) ss[wave] = sum;
    __syncthreads();
    sum = ss[0] + ss[1] + ss[2] + ss[3];
    float inv = 1.0f / sum;
    for (int i = tid; i < n; i += 256) out[i] = __expf(lg[i] - mx) * mk[i] * inv;
}

// K3: weighted pooling with coalesced half8 loads. Block = (b, 128-position chunk).
// Thread (g=tid>>5, c=tid&31): owns d-slice [8c,8c+8), strides g over positions.
template <bool F16SRC>
__global__ __launch_bounds__(256) void k3(const float* __restrict__ docf, const float* __restrict__ qryf,
                                          const _Float16* __restrict__ dh, const _Float16* __restrict__ qh,
                                          const float* __restrict__ alpha, const float* __restrict__ beta,
                                          float* __restrict__ out) {
    __shared__ float sm[8 * DD];
    int blk = blockIdx.x, tid = threadIdx.x;
    const _Float16* srch;
    const float* srcf;
    const float* w;
    float* dst;
    if (blk < BB * 16) {
        int b = blk >> 4, ch = blk & 15;
        srch = dh + ((size_t)b * LD + ch * 128) * DD;
        srcf = docf + ((size_t)b * LD + ch * 128) * DD;
        w = alpha + b * LD + ch * 128;
        dst = out + b * 2 * DD;
    } else {
        int k = blk - BB * 16;
        int b = k >> 2, ch = k & 3;
        srch = qh + ((size_t)b * LQ + ch * 128) * DD;
        srcf = qryf + ((size_t)b * LQ + ch * 128) * DD;
        w = beta + b * LQ + ch * 128;
        dst = out + b * 2 * DD + DD;
    }
    int g = tid >> 5, c = tid & 31;
    float acc[8];
#pragma unroll
    for (int j = 0; j < 8; j++) acc[j] = 0.f;
    for (int r = 0; r < 16; r++) {
        int t = r * 8 + g;
        float wt = w[t];
        if constexpr (F16SRC) {
            half8 x = *(const half8*)(srch + (size_t)t * DD + c * 8);
#pragma unroll
            for (int j = 0; j < 8; j++) acc[j] += wt * (float)x[j];
        } else {
            const float4v* p = (const float4v*)(srcf + (size_t)t * DD + c * 8);
            float4v x0 = p[0], x1 = p[1];
#pragma unroll
            for (int j = 0; j < 4; j++) { acc[j] += wt * x0[j]; acc[4 + j] += wt * x1[j]; }
        }
    }
#pragma unroll
    for (int j = 0; j < 8; j++) sm[g * DD + c * 8 + j] = acc[j];
    __syncthreads();
    float s = 0.f;
#pragma unroll
    for (int g2 = 0; g2 < 8; g2++) s += sm[g2 * DD + tid];
    atomicAdd(dst + tid, s);
}

extern "C" void kernel_launch(void* const* d_in, const int* in_sizes, int n_in,
                              void* d_out, int out_size, void* d_ws, size_t ws_size,
                              hipStream_t stream) {
    (void)in_sizes; (void)n_in; (void)out_size;
    const float* doc = (const float*)d_in[0];
    const float* qry = (const float*)d_in[1];
    const float* dmask = (const float*)d_in[2];
    const float* qmask = (const float*)d_in[3];
    float* out = (float*)d_out;

    float* alog = (float*)d_ws;                 // [B][LD]
    float* blog = alog + BB * LD;               // [B][LQ]
    float* alpha = blog + BB * LQ;              // [B][LD]
    float* beta = alpha + BB * LD;              // [B][LQ]
    _Float16* dh = (_Float16*)(beta + BB * LQ); // [B][LD][D] f16
    _Float16* qh = dh + (size_t)BB * LD * DD;   // [B][LQ][D] f16
    size_t needed = (size_t)(2 * BB * LD + 2 * BB * LQ) * 4 +
                    ((size_t)BB * LD * DD + (size_t)BB * LQ * DD) * 2;
    bool useF16 = ws_size >= needed;

    hipMemsetAsync(alog, 0, (size_t)(BB * LD + BB * LQ) * 4, stream);
    hipMemsetAsync(d_out, 0, (size_t)BB * 2 * DD * 4, stream);

    if (useF16) {
        kconv<<<(DOCN8 + QRYN8) / 256, 256, 0, stream>>>(doc, qry, dh, qh);
        k1<true><<<dim3(LQ / BM, LD / BN, BB), 256, 0, stream>>>(qh, dh, alog, blog);
    } else {
        k1<false><<<dim3(LQ / BM, LD / BN, BB), 256, 0, stream>>>(qry, doc, alog, blog);
    }
    k2<<<2 * BB, 256, 0, stream>>>(alog, blog, dmask, qmask, alpha, beta);
    if (useF16) {
        k3<true><<<BB * 16 + BB * 4, 256, 0, stream>>>(doc, qry, dh, qh, alpha, beta, out);
    } else {
        k3<false><<<BB * 16 + BB * 4, 256, 0, stream>>>(doc, qry, dh, qh, alpha, beta, out);
    }
}